// Round 18
// baseline (338.109 us; speedup 1.0000x reference)
//
#include <hip/hip_runtime.h>
#include <hip/hip_bf16.h>
#include <math.h>
#include <stdint.h>

// Problem constants
#define S_LEN 2048
#define NH    32
#define NKV   8
#define HD    128
#define HIDD  4096

typedef unsigned short u16;
typedef __attribute__((ext_vector_type(4))) int i32x4;   // 16B = MFMA i8 frag / 4 i32 acc

// async global->LDS, 16B per lane. LDS dest is wave-uniform base + lane*16.
#define GLD16(g, l) __builtin_amdgcn_global_load_lds( \
    (const __attribute__((address_space(1))) void*)(g), \
    (__attribute__((address_space(3))) void*)(l), 16, 0, 0)

// ---------- helpers ----------

__device__ __forceinline__ float slot_scale(const unsigned* slot) {
    return fmaxf(__uint_as_float(*slot), 1e-5f) / 127.0f;
}

__device__ __forceinline__ float exp2_fast(float x) {
    float r; asm("v_exp_f32 %0, %1" : "=v"(r) : "v"(x)); return r;
}
__device__ __forceinline__ float log2_fast(float x) {
    float r; asm("v_log_f32 %0, %1" : "=v"(r) : "v"(x)); return r;
}

// quantize to integer in [-128,127]
__device__ __forceinline__ int qint(float x, float s) {
    float q = rintf(x / s);
    q = fminf(fmaxf(q, -128.0f), 127.0f);
    return (int)q;
}

__device__ __forceinline__ void block_amax_atomic(float m, unsigned* slot) {
    __shared__ float wmax[8];
    const int lane = threadIdx.x & 63;
    const int wid  = threadIdx.x >> 6;
    const int nw   = blockDim.x >> 6;
    #pragma unroll
    for (int o = 32; o; o >>= 1) m = fmaxf(m, __shfl_xor(m, o));
    if (lane == 0) wmax[wid] = m;
    __syncthreads();
    if (threadIdx.x == 0) {
        float bm = wmax[0];
        for (int i = 1; i < nw; ++i) bm = fmaxf(bm, wmax[i]);
        atomicMax(slot, __float_as_uint(bm));
    }
}

// ---------- batched absmax over 5 f32 tensors ----------
struct Amax5Args { const float* p[5]; size_t n4[5]; };
__global__ __launch_bounds__(256) void absmax5_kernel(Amax5Args a, unsigned* slots) {
    const int t = blockIdx.y;
    const float4* x4 = (const float4*)a.p[t];
    const size_t n4 = a.n4[t];
    size_t i = (size_t)blockIdx.x * blockDim.x + threadIdx.x;
    size_t stride = (size_t)gridDim.x * blockDim.x;
    float m = 0.0f;
    for (; i < n4; i += stride) {
        float4 v = x4[i];
        m = fmaxf(m, fmaxf(fmaxf(fabsf(v.x), fabsf(v.y)), fmaxf(fabsf(v.z), fabsf(v.w))));
    }
    block_amax_atomic(m, slots + t);
}

// ---------- batched quantize of 5 f32 tensors -> int8 ----------
struct Quant5Args { const float* p[5]; char* o[5]; size_t n4[5]; };
__global__ __launch_bounds__(256) void quant5_kernel(Quant5Args a, const unsigned* slots) {
    const int t = blockIdx.y;
    float s = slot_scale(slots + t);
    const float4* x4 = (const float4*)a.p[t];
    unsigned* o4 = (unsigned*)a.o[t];
    const size_t n4 = a.n4[t];
    size_t i = (size_t)blockIdx.x * blockDim.x + threadIdx.x;
    size_t stride = (size_t)gridDim.x * blockDim.x;
    for (; i < n4; i += stride) {
        float4 v = x4[i];
        unsigned o = (unsigned)(qint(v.x, s) & 255)
                   | ((unsigned)(qint(v.y, s) & 255) << 8)
                   | ((unsigned)(qint(v.z, s) & 255) << 16)
                   | ((unsigned)(qint(v.w, s) & 255) << 24);
        o4[i] = o;
    }
}

// ---------- plain quantize (attn output) ----------
__global__ __launch_bounds__(256) void quant_kernel(const float* __restrict__ x,
                                                    size_t n4, const unsigned* slot,
                                                    char* __restrict__ out) {
    float s = slot_scale(slot);
    size_t i = (size_t)blockIdx.x * blockDim.x + threadIdx.x;
    size_t stride = (size_t)gridDim.x * blockDim.x;
    const float4* x4 = (const float4*)x;
    unsigned* o4 = (unsigned*)out;
    for (; i < n4; i += stride) {
        float4 v = x4[i];
        unsigned o = (unsigned)(qint(v.x, s) & 255)
                   | ((unsigned)(qint(v.y, s) & 255) << 8)
                   | ((unsigned)(qint(v.z, s) & 255) << 16)
                   | ((unsigned)(qint(v.w, s) & 255) << 24);
        o4[i] = o;
    }
}

// ---------- i8 GEMM body: 128x128 tile, BK=64, 3-stage pipeline (R12 best) ----------
__device__ __forceinline__ void gemm_body(const char* __restrict__ A,
                                          const char* __restrict__ B,
                                          float* __restrict__ C,
                                          int m0, int n0, int N, int K,
                                          float scale, unsigned* out_amax,
                                          char* Asm, char* Bsm) {
    const int tid  = threadIdx.x;
    const int lane = tid & 63;
    const int wave = tid >> 6;
    const int wr = (wave >> 1) * 64;
    const int wc = (wave & 1) * 64;
    const int l15 = lane & 15;
    const int l4  = lane >> 4;
    const int cx  = (l4 ^ (l15 & 3)) * 16;          // swizzled frag-read col
    const int r0  = tid >> 2;                        // staging row
    const int sc  = ((tid & 3) ^ ((tid >> 2) & 3)) * 16;  // pre-swizzled source col

    i32x4 acc[4][4];
    #pragma unroll
    for (int i = 0; i < 4; ++i)
        #pragma unroll
        for (int j = 0; j < 4; ++j) acc[i][j] = (i32x4){0, 0, 0, 0};

    auto STAGE = [&](int buf, int k0) {
        GLD16(&A[(size_t)(m0 + r0) * K + k0 + sc],      &Asm[buf * 8192 + wave * 1024]);
        GLD16(&A[(size_t)(m0 + 64 + r0) * K + k0 + sc], &Asm[buf * 8192 + 4096 + wave * 1024]);
        GLD16(&B[(size_t)(n0 + r0) * K + k0 + sc],      &Bsm[buf * 8192 + wave * 1024]);
        GLD16(&B[(size_t)(n0 + 64 + r0) * K + k0 + sc], &Bsm[buf * 8192 + 4096 + wave * 1024]);
    };

    const int NT = K >> 6;
    STAGE(0, 0);
    STAGE(1, 64);
    int cur = 0;
    for (int t = 0; t < NT; ++t) {
        if (t + 1 < NT) {
            asm volatile("s_waitcnt vmcnt(4)" ::: "memory");   // STAGE(t) landed
        } else {
            asm volatile("s_waitcnt vmcnt(0)" ::: "memory");   // last: drain all
        }
        __builtin_amdgcn_sched_barrier(0);
        __builtin_amdgcn_s_barrier();                          // raw: no vm drain
        __builtin_amdgcn_sched_barrier(0);
        if (t + 2 < NT) {
            int nb = cur + 2; if (nb >= 3) nb -= 3;
            STAGE(nb, (t + 2) << 6);                           // overwrites buf[t-1]
        }
        i32x4 af[4], bfr[4];
        #pragma unroll
        for (int i = 0; i < 4; ++i)
            af[i] = *(const i32x4*)&Asm[cur * 8192 + (wr + i * 16 + l15) * 64 + cx];
        #pragma unroll
        for (int j = 0; j < 4; ++j)
            bfr[j] = *(const i32x4*)&Bsm[cur * 8192 + (wc + j * 16 + l15) * 64 + cx];
        #pragma unroll
        for (int i = 0; i < 4; ++i)
            #pragma unroll
            for (int j = 0; j < 4; ++j)
                acc[i][j] = __builtin_amdgcn_mfma_i32_16x16x64_i8(af[i], bfr[j], acc[i][j], 0, 0, 0);
        cur += 1; if (cur == 3) cur = 0;
    }

    float lm = 0.0f;
    #pragma unroll
    for (int i = 0; i < 4; ++i)
        #pragma unroll
        for (int j = 0; j < 4; ++j)
            #pragma unroll
            for (int r = 0; r < 4; ++r) {
                int row = m0 + wr + i * 16 + l4 * 4 + r;
                int col = n0 + wc + j * 16 + l15;
                float v = (float)acc[i][j][r] * scale;
                C[(size_t)row * N + col] = v;
                lm = fmaxf(lm, fabsf(v));
            }
    __syncthreads();   // re-align waves before block_amax
    if (out_amax) block_amax_atomic(lm, out_amax);
}

// fused Q,K,V projections: grid 768 = 16 m-tiles x 48 n-blocks (32 Q | 8 K | 8 V)
__global__ __launch_bounds__(256) void gemm_qkv_kernel(const char* __restrict__ Aq,
                                                       const char* __restrict__ Wqq,
                                                       const char* __restrict__ Wkq,
                                                       const char* __restrict__ Wvq,
                                                       float* __restrict__ qf,
                                                       float* __restrict__ kf,
                                                       float* __restrict__ vf,
                                                       const unsigned* __restrict__ slots,
                                                       unsigned* v_amax) {
    __shared__ __align__(16) char Asm[3 * 8192];
    __shared__ __align__(16) char Bsm[3 * 8192];
    int bid = blockIdx.x;
    int swz = (bid & 7) * 96 + (bid >> 3);      // bijective XCD swizzle (768 % 8 == 0)
    int x = swz & 15, y = swz >> 4;
    const char* B; float* C; int N, nb; const unsigned* sB; unsigned* am = nullptr;
    if (y < 32)      { B = Wqq; C = qf; N = NH * HD;  nb = y;      sB = slots + 1; }
    else if (y < 40) { B = Wkq; C = kf; N = NKV * HD; nb = y - 32; sB = slots + 2; }
    else             { B = Wvq; C = vf; N = NKV * HD; nb = y - 40; sB = slots + 3; am = v_amax; }
    float scale = slot_scale(slots + 0) * slot_scale(sB);
    gemm_body(Aq, B, C, x * 128, nb * 128, N, HIDD, scale, am, Asm, Bsm);
}

// O-projection: grid 512 = 16 x 32
__global__ __launch_bounds__(256) void gemm_o_kernel(const char* __restrict__ A,
                                                     const char* __restrict__ Woq,
                                                     float* __restrict__ C,
                                                     const unsigned* __restrict__ slots) {
    __shared__ __align__(16) char Asm[3 * 8192];
    __shared__ __align__(16) char Bsm[3 * 8192];
    int bid = blockIdx.x;
    int swz = (bid & 7) * 64 + (bid >> 3);      // 512 % 8 == 0
    int x = swz & 15, y = swz >> 4;
    float scale = slot_scale(slots + 8) * slot_scale(slots + 4);
    gemm_body(A, Woq, C, x * 128, y * 128, NH * HD, HIDD, scale, nullptr, Asm, Bsm);
}

// ---------- RMSNorm + RoPE for q (y=0) and k (y=1), in-place, + absmax ----------
// cos/sin symmetry: emb = concat([freqs,freqs]) -> cos[s][d] == cos[s][d+64];
// load only cols 0..63 (one factor per lane serves both halves).
__global__ __launch_bounds__(256) void rmsrope2_kernel(float* __restrict__ qx,
                                                       float* __restrict__ kx,
                                                       const float* __restrict__ cosb,
                                                       const float* __restrict__ sinb,
                                                       const float* __restrict__ qw,
                                                       const float* __restrict__ kw,
                                                       unsigned* slots) {
    const int which = blockIdx.y;
    float* x = which ? kx : qx;
    const float* w = which ? kw : qw;
    const int s_shift = which ? 3 : 5;
    const int nrows = which ? (S_LEN * NKV) : (S_LEN * NH);
    unsigned* slot = slots + (which ? 6 : 5);

    const int lane = threadIdx.x & 63;
    const int wid  = threadIdx.x >> 6;
    const float wa = w[lane];
    const float wb = w[lane + 64];
    float lm = 0.0f;
    for (int row = blockIdx.x * 4 + wid; row < nrows; row += gridDim.x * 4) {
        int s = row >> s_shift;
        float* xr = x + (size_t)row * 128;
        float a = xr[lane], b = xr[lane + 64];
        float ss = a * a + b * b;
        #pragma unroll
        for (int o = 32; o; o >>= 1) ss += __shfl_xor(ss, o);
        float inv = 1.0f / sqrtf(ss * (1.0f / 128.0f) + 1e-5f);
        float ya = (a * inv) * wa;
        float yb = (b * inv) * wb;
        float c = cosb[(size_t)s * 128 + lane];   // == cosb[s][lane+64]
        float sn = sinb[(size_t)s * 128 + lane];  // == sinb[s][lane+64]
        float o0 = ya * c - yb * sn;
        float o1 = yb * c + ya * sn;
        xr[lane] = o0;
        xr[lane + 64] = o1;
        lm = fmaxf(lm, fmaxf(fabsf(o0), fabsf(o1)));
    }
    block_amax_atomic(lm, slot);
}

// ---------- merged quantize: v transpose (bx<1024) + q/k reorder ----------
__global__ __launch_bounds__(256) void quant_qkv_kernel(const float* __restrict__ qx,
                                                        const float* __restrict__ kx,
                                                        const float* __restrict__ vx,
                                                        const unsigned* slots,
                                                        char* __restrict__ qq,
                                                        char* __restrict__ kq,
                                                        char* __restrict__ vtq) {
    const int bx = blockIdx.x;
    if (bx < 1024) {
        __shared__ unsigned char t8[64][36];
        const float s = slot_scale(slots + 7);
        const int t   = threadIdx.x;
        const int kvh = bx >> 7;
        const int rem = bx & 127;
        const int d0  = (rem & 3) * 32;
        const int sp0 = (rem >> 2) * 64;
        const int dl = t & 31;
        const int sb = t >> 5;
        #pragma unroll
        for (int j = 0; j < 8; ++j) {
            int spl = sb + j * 8;
            float v = vx[((size_t)(sp0 + spl) * NKV + kvh) * 128 + d0 + dl];
            t8[spl][dl] = (unsigned char)qint(v, s);
        }
        __syncthreads();
        const int dd = t >> 3;
        const int ch = t & 7;
        unsigned lo = 0, hi = 0;
        #pragma unroll
        for (int j = 0; j < 4; ++j) lo |= (unsigned)t8[ch * 8 + j][dd] << (8 * j);
        #pragma unroll
        for (int j = 0; j < 4; ++j) hi |= (unsigned)t8[ch * 8 + 4 + j][dd] << (8 * j);
        *(uint2*)&vtq[((size_t)kvh * 128 + d0 + dd) * S_LEN + sp0 + ch * 8] = make_uint2(lo, hi);
        return;
    }
    int tid = (bx - 1024) * 256 + threadIdx.x;         // one per 4 elements
    const int qtot4 = S_LEN * NH * HD / 4;
    if (tid < qtot4) {
        float s = slot_scale(slots + 5);
        int e = tid * 4;
        int d  = e & 127;
        int h  = (e >> 7) & 31;
        int sp = e >> 12;
        float4 v = *(const float4*)&qx[e];
        uchar4 o;
        o.x = (unsigned char)qint(v.x, s); o.y = (unsigned char)qint(v.y, s);
        o.z = (unsigned char)qint(v.z, s); o.w = (unsigned char)qint(v.w, s);
        *(uchar4*)&qq[((size_t)h * S_LEN + sp) * 128 + d] = o;
    } else {
        tid -= qtot4;
        float s = slot_scale(slots + 6);
        int e = tid * 4;
        int d  = e & 127;
        int h  = (e >> 7) & 7;
        int sp = e >> 10;
        float4 v = *(const float4*)&kx[e];
        uchar4 o;
        o.x = (unsigned char)qint(v.x, s); o.y = (unsigned char)qint(v.y, s);
        o.z = (unsigned char)qint(v.z, s); o.w = (unsigned char)qint(v.w, s);
        *(uchar4*)&kq[((size_t)h * S_LEN + sp) * 128 + d] = o;
    }
}

// ---------- attention: two-pass flash, all-int8 MFMA, 8-wave TLP tile pair ----------
// T13 defer-max in pass 1: skip the rescale (and its exp2 on the serial chain)
// unless the block max exceeds the running max by >8 (exp2 headroom 256, exact
// after the merge rescale). Wave-uniform branch via __any.
__global__ __launch_bounds__(512) void attn_kernel(const char* __restrict__ Qq,
                                                   const char* __restrict__ Kq,
                                                   const char* __restrict__ Vt,
                                                   const unsigned* sq_slot,
                                                   const unsigned* sk_slot,
                                                   const unsigned* sv_slot,
                                                   float* __restrict__ O,
                                                   unsigned* amax_slot) {
    __shared__ __align__(16) char Klds[64 * 144];     // stride 144B
    __shared__ __align__(16) char Vlds[128 * 80];     // stride 80B
    __shared__ __align__(16) char plds[8][16 * 80];   // per-wave P tile

    const int tid  = threadIdx.x;
    const int lane = tid & 63;
    const int wave = tid >> 6;          // 0..7
    const int mw   = wave & 3;          // sub-row within tile
    const int h  = blockIdx.y;
    const int kv = h >> 2;
    const int l15 = lane & 15;
    const int l4  = lane >> 4;
    const size_t kvS = (size_t)kv * S_LEN;

    const int qtS = blockIdx.x;           // 0..15
    const int qtB = 31 - qtS;             // 16..31
    const int my_qt = (wave < 4) ? qtB : qtS;
    const int qr0 = my_qt * 64 + mw * 16;

    const float sq = slot_scale(sq_slot);
    const float sk = slot_scale(sk_slot);
    const float sv = slot_scale(sv_slot);
    const float qs2 = sq * sk * 0.08838834764831845f * 1.4426950408889634f; // *log2(e)
    const float osc = (1.0f / 127.0f) * sv;   // s_p exactly 1/127 (row 0 => max p = 1.0)
    const float NEG = -1e30f;

    const int krow = tid >> 3, kcol = (tid & 7) * 16;   // 64 x 128B
    const int vrow = tid >> 2, vcol = (tid & 3) * 16;   // 128 x 64B

    i32x4 qf2[2];
    {
        const char* qp = Qq + ((size_t)h * S_LEN + qr0 + l15) * 128 + l4 * 16;
        qf2[0] = *(const i32x4*)(qp);
        qf2[1] = *(const i32x4*)(qp + 64);
    }

    auto qk_block = [&](int hb) -> i32x4 {
        i32x4 sacc = {0, 0, 0, 0};
        #pragma unroll
        for (int c = 0; c < 2; ++c) {
            i32x4 kfa = *(const i32x4*)&Klds[(hb * 16 + l15) * 144 + c * 64 + l4 * 16];
            sacc = __builtin_amdgcn_mfma_i32_16x16x64_i8(kfa, qf2[c], sacc, 0, 0, 0);
        }
        return sacc;
    };

    // ================= pass 1: lane-local online m,l with defer-max ==========
    float m_l = NEG, l_l = 0.0f;

    auto p1_update = [&](float x0, float x1, float x2, float x3) {
        float bm = fmaxf(fmaxf(x0, x1), fmaxf(x2, x3));
        if (__any(bm > m_l + 8.0f)) {          // rare: rescale path
            float mn = fmaxf(m_l, bm);
            l_l = l_l * exp2_fast(m_l - mn)
                + exp2_fast(x0 - mn) + exp2_fast(x1 - mn)
                + exp2_fast(x2 - mn) + exp2_fast(x3 - mn);
            m_l = mn;
        } else {                                // common: keep old max
            l_l += exp2_fast(x0 - m_l) + exp2_fast(x1 - m_l)
                 + exp2_fast(x2 - m_l) + exp2_fast(x3 - m_l);
        }
    };
    auto p1_interior = [&](int hb) {
        i32x4 sacc = qk_block(hb);
        p1_update((float)sacc[0] * qs2, (float)sacc[1] * qs2,
                  (float)sacc[2] * qs2, (float)sacc[3] * qs2);
    };
    auto p1_diag = [&](int hb) {
        i32x4 sacc = qk_block(hb);
        float x[4];
        #pragma unroll
        for (int r = 0; r < 4; ++r) {
            float v = (float)sacc[r] * qs2;
            x[r] = ((l4 * 4 + r) > l15) ? NEG : v;
        }
        p1_update(x[0], x[1], x[2], x[3]);
    };

    i32x4 kreg = *(const i32x4*)&Kq[(kvS + krow) * 128 + kcol];
    #pragma unroll 1
    for (int kc = 0; kc <= qtB; ++kc) {
        __syncthreads();
        *(i32x4*)&Klds[krow * 144 + kcol] = kreg;
        __syncthreads();
        if (kc < qtB)
            kreg = *(const i32x4*)&Kq[(kvS + (kc + 1) * 64 + krow) * 128 + kcol];
        if (kc < my_qt) {
            p1_interior(0); p1_interior(1); p1_interior(2); p1_interior(3);
        } else if (kc == my_qt) {
            #pragma unroll
            for (int hb = 0; hb < 4; ++hb) {
                if (hb < mw) p1_interior(hb);
                else if (hb == mw) p1_diag(hb);
            }
        }
    }
    float cmy;
    {
        float m2 = fmaxf(m_l, __shfl_xor(m_l, 16));
        float mfin = fmaxf(m2, __shfl_xor(m2, 32));
        float t = l_l * exp2_fast(m_l - mfin);
        t += __shfl_xor(t, 16);
        t += __shfl_xor(t, 32);
        cmy = mfin - log2_fast(127.0f / t);
    }

    // ================= pass 2: quantized P @ V (i8), my tile only ============
    i32x4 oacc[8];
    #pragma unroll
    for (int dt = 0; dt < 8; ++dt) oacc[dt] = (i32x4){0, 0, 0, 0};

    auto p2_interior = [&](int hb) -> unsigned {
        i32x4 sacc = qk_block(hb);
        unsigned pack = 0;
        #pragma unroll
        for (int r = 0; r < 4; ++r) {
            float pq = rintf(exp2_fast(fmaf((float)sacc[r], qs2, -cmy)));
            pack |= ((unsigned)(int)pq) << (8 * r);
        }
        return pack;
    };
    auto p2_diag = [&](int hb) -> unsigned {
        i32x4 sacc = qk_block(hb);
        unsigned pack = 0;
        #pragma unroll
        for (int r = 0; r < 4; ++r) {
            float p = exp2_fast(fmaf((float)sacc[r], qs2, -cmy));
            float pq = ((l4 * 4 + r) > l15) ? 0.0f : rintf(p);
            pack |= ((unsigned)(int)pq) << (8 * r);
        }
        return pack;
    };
    auto pv8 = [&]() {
        i32x4 pf = *(const i32x4*)&plds[wave][l15 * 80 + l4 * 16];
        __builtin_amdgcn_s_setprio(1);
        #pragma unroll
        for (int dt = 0; dt < 8; ++dt) {
            i32x4 vfb = *(const i32x4*)&Vlds[(dt * 16 + l15) * 80 + l4 * 16];
            oacc[dt] = __builtin_amdgcn_mfma_i32_16x16x64_i8(pf, vfb, oacc[dt], 0, 0, 0);
        }
        __builtin_amdgcn_s_setprio(0);
    };

    kreg = *(const i32x4*)&Kq[(kvS + krow) * 128 + kcol];
    i32x4 vreg = *(const i32x4*)&Vt[((size_t)kv * 128 + vrow) * S_LEN + vcol];
    #pragma unroll 1
    for (int kc = 0; kc <= qtB; ++kc) {
        __syncthreads();
        *(i32x4*)&Klds[krow * 144 + kcol] = kreg;
        *(i32x4*)&Vlds[vrow * 80 + vcol] = vreg;
        __syncthreads();
        if (kc < qtB) {
            kreg = *(const i32x4*)&Kq[(kvS + (kc + 1) * 64 + krow) * 128 + kcol];
            vreg = *(const i32x4*)&Vt[((size_t)kv * 128 + vrow) * S_LEN + (kc + 1) * 64 + vcol];
        }
        if (kc < my_qt) {
            #pragma unroll
            for (int hb = 0; hb < 4; ++hb)
                *(unsigned*)&plds[wave][l15 * 80 + hb * 16 + l4 * 4] = p2_interior(hb);
            pv8();
        } else if (kc == my_qt) {
            #pragma unroll
            for (int hb = 0; hb < 4; ++hb) {
                unsigned pack = 0;
                if (hb < mw) pack = p2_interior(hb);
                else if (hb == mw) pack = p2_diag(hb);
                *(unsigned*)&plds[wave][l15 * 80 + hb * 16 + l4 * 4] = pack;
            }
            pv8();
        }
    }

    float lm = 0.0f;
    #pragma unroll
    for (int dt = 0; dt < 8; ++dt)
        #pragma unroll
        for (int r = 0; r < 4; ++r) {
            float v = (float)oacc[dt][r] * osc;
            O[(size_t)(qr0 + l4 * 4 + r) * (NH * 128) + h * 128 + dt * 16 + l15] = v;
            lm = fmaxf(lm, fabsf(v));
        }
    block_amax_atomic(lm, amax_slot);
}

// ---------- host ----------
extern "C" void kernel_launch(void* const* d_in, const int* in_sizes, int n_in,
                              void* d_out, int out_size, void* d_ws, size_t ws_size,
                              hipStream_t stream) {
    const float* hs   = (const float*)d_in[0];
    const float* cosb = (const float*)d_in[1];
    const float* sinb = (const float*)d_in[2];
    const float* Wq   = (const float*)d_in[4];
    const float* Wk   = (const float*)d_in[5];
    const float* Wv   = (const float*)d_in[6];
    const float* Wo   = (const float*)d_in[7];
    const float* qnw  = (const float*)d_in[8];
    const float* knw  = (const float*)d_in[9];
    float* out = (float*)d_out;

    char* ws = (char*)d_ws;
    unsigned* slots = (unsigned*)ws;
    // slots: 0 hs, 1 Wq, 2 Wk, 3 Wv, 4 Wo, 5 q, 6 k, 7 v, 8 attn
    size_t off = 256;
    auto take = [&](size_t bytes) { size_t o = off; off += (bytes + 255) & ~(size_t)255; return o; };
    char*  hsq  = (char*)(ws + take((size_t)S_LEN * HIDD));
    char*  Wqq  = (char*)(ws + take((size_t)NH * HD * HIDD));
    char*  Wkq  = (char*)(ws + take((size_t)NKV * HD * HIDD));
    char*  Wvq  = (char*)(ws + take((size_t)NKV * HD * HIDD));
    char*  Woq  = (char*)(ws + take((size_t)HIDD * NH * HD));
    float* qf   = (float*)(ws + take((size_t)S_LEN * NH * HD * 4));
    float* kf   = (float*)(ws + take((size_t)S_LEN * NKV * HD * 4));
    float* vf   = (float*)(ws + take((size_t)S_LEN * NKV * HD * 4));
    char*  qq   = (char*)(ws + take((size_t)NH * S_LEN * HD));
    char*  kq   = (char*)(ws + take((size_t)NKV * S_LEN * HD));
    char*  vtq  = (char*)(ws + take((size_t)NKV * HD * S_LEN));
    float* attnf = qf;     // q f32 dead after quant_qkv
    char*  attnq = hsq;    // hs_q dead after the projections

    hipMemsetAsync(ws, 0, 64, stream);

    const size_t n_hs = (size_t)S_LEN * HIDD;
    const size_t n_wq = (size_t)NH * HD * HIDD;
    const size_t n_wk = (size_t)NKV * HD * HIDD;

    Amax5Args aa;
    aa.p[0] = hs; aa.p[1] = Wq; aa.p[2] = Wk; aa.p[3] = Wv; aa.p[4] = Wo;
    aa.n4[0] = n_hs / 4; aa.n4[1] = n_wq / 4; aa.n4[2] = n_wk / 4;
    aa.n4[3] = n_wk / 4; aa.n4[4] = n_wq / 4;
    absmax5_kernel<<<dim3(512, 5), 256, 0, stream>>>(aa, slots);

    Quant5Args qa;
    qa.p[0] = hs; qa.p[1] = Wq; qa.p[2] = Wk; qa.p[3] = Wv; qa.p[4] = Wo;
    qa.o[0] = hsq; qa.o[1] = Wqq; qa.o[2] = Wkq; qa.o[3] = Wvq; qa.o[4] = Woq;
    qa.n4[0] = n_hs / 4; qa.n4[1] = n_wq / 4; qa.n4[2] = n_wk / 4;
    qa.n4[3] = n_wk / 4; qa.n4[4] = n_wq / 4;
    quant5_kernel<<<dim3(1024, 5), 256, 0, stream>>>(qa, slots);

    gemm_qkv_kernel<<<768, 256, 0, stream>>>(hsq, Wqq, Wkq, Wvq, qf, kf, vf,
                                             slots, slots + 7);

    rmsrope2_kernel<<<dim3(1024, 2), 256, 0, stream>>>(qf, kf, cosb, sinb, qnw, knw, slots);

    quant_qkv_kernel<<<1024 + 10240, 256, 0, stream>>>(qf, kf, vf, slots, qq, kq, vtq);

    attn_kernel<<<dim3(16, NH), 512, 0, stream>>>(qq, kq, vtq,
                                                  slots + 5, slots + 6, slots + 7,
                                                  attnf, slots + 8);

    quant_kernel<<<2048, 256, 0, stream>>>(attnf, n_hs / 4, slots + 8, attnq);
    gemm_o_kernel<<<512, 256, 0, stream>>>(attnq, Woq, out, slots);
    (void)in_sizes; (void)n_in; (void)out_size; (void)ws_size;
}

// Round 19
// 335.868 us; speedup vs baseline: 1.0067x; 1.0067x over previous
//
#include <hip/hip_runtime.h>
#include <hip/hip_bf16.h>
#include <math.h>
#include <stdint.h>

// Problem constants
#define S_LEN 2048
#define NH    32
#define NKV   8
#define HD    128
#define HIDD  4096

typedef unsigned short u16;
typedef __attribute__((ext_vector_type(4))) int i32x4;   // 16B = MFMA i8 frag / 4 i32 acc

// async global->LDS, 16B per lane. LDS dest is wave-uniform base + lane*16.
#define GLD16(g, l) __builtin_amdgcn_global_load_lds( \
    (const __attribute__((address_space(1))) void*)(g), \
    (__attribute__((address_space(3))) void*)(l), 16, 0, 0)

// ---------- helpers ----------

__device__ __forceinline__ float slot_scale(const unsigned* slot) {
    return fmaxf(__uint_as_float(*slot), 1e-5f) / 127.0f;
}

__device__ __forceinline__ float exp2_fast(float x) {
    float r; asm("v_exp_f32 %0, %1" : "=v"(r) : "v"(x)); return r;
}
__device__ __forceinline__ float log2_fast(float x) {
    float r; asm("v_log_f32 %0, %1" : "=v"(r) : "v"(x)); return r;
}

// quantize to integer in [-128,127]
__device__ __forceinline__ int qint(float x, float s) {
    float q = rintf(x / s);
    q = fminf(fmaxf(q, -128.0f), 127.0f);
    return (int)q;
}

__device__ __forceinline__ void block_amax_atomic(float m, unsigned* slot) {
    __shared__ float wmax[8];
    const int lane = threadIdx.x & 63;
    const int wid  = threadIdx.x >> 6;
    const int nw   = blockDim.x >> 6;
    #pragma unroll
    for (int o = 32; o; o >>= 1) m = fmaxf(m, __shfl_xor(m, o));
    if (lane == 0) wmax[wid] = m;
    __syncthreads();
    if (threadIdx.x == 0) {
        float bm = wmax[0];
        for (int i = 1; i < nw; ++i) bm = fmaxf(bm, wmax[i]);
        atomicMax(slot, __float_as_uint(bm));
    }
}

// ---------- batched absmax over 5 f32 tensors ----------
struct Amax5Args { const float* p[5]; size_t n4[5]; };
__global__ __launch_bounds__(256) void absmax5_kernel(Amax5Args a, unsigned* slots) {
    const int t = blockIdx.y;
    const float4* x4 = (const float4*)a.p[t];
    const size_t n4 = a.n4[t];
    size_t i = (size_t)blockIdx.x * blockDim.x + threadIdx.x;
    size_t stride = (size_t)gridDim.x * blockDim.x;
    float m = 0.0f;
    for (; i < n4; i += stride) {
        float4 v = x4[i];
        m = fmaxf(m, fmaxf(fmaxf(fabsf(v.x), fabsf(v.y)), fmaxf(fabsf(v.z), fabsf(v.w))));
    }
    block_amax_atomic(m, slots + t);
}

// ---------- batched quantize of 5 f32 tensors -> int8 ----------
struct Quant5Args { const float* p[5]; char* o[5]; size_t n4[5]; };
__global__ __launch_bounds__(256) void quant5_kernel(Quant5Args a, const unsigned* slots) {
    const int t = blockIdx.y;
    float s = slot_scale(slots + t);
    const float4* x4 = (const float4*)a.p[t];
    unsigned* o4 = (unsigned*)a.o[t];
    const size_t n4 = a.n4[t];
    size_t i = (size_t)blockIdx.x * blockDim.x + threadIdx.x;
    size_t stride = (size_t)gridDim.x * blockDim.x;
    for (; i < n4; i += stride) {
        float4 v = x4[i];
        unsigned o = (unsigned)(qint(v.x, s) & 255)
                   | ((unsigned)(qint(v.y, s) & 255) << 8)
                   | ((unsigned)(qint(v.z, s) & 255) << 16)
                   | ((unsigned)(qint(v.w, s) & 255) << 24);
        o4[i] = o;
    }
}

// ---------- plain quantize (attn output) ----------
__global__ __launch_bounds__(256) void quant_kernel(const float* __restrict__ x,
                                                    size_t n4, const unsigned* slot,
                                                    char* __restrict__ out) {
    float s = slot_scale(slot);
    size_t i = (size_t)blockIdx.x * blockDim.x + threadIdx.x;
    size_t stride = (size_t)gridDim.x * blockDim.x;
    const float4* x4 = (const float4*)x;
    unsigned* o4 = (unsigned*)out;
    for (; i < n4; i += stride) {
        float4 v = x4[i];
        unsigned o = (unsigned)(qint(v.x, s) & 255)
                   | ((unsigned)(qint(v.y, s) & 255) << 8)
                   | ((unsigned)(qint(v.z, s) & 255) << 16)
                   | ((unsigned)(qint(v.w, s) & 255) << 24);
        o4[i] = o;
    }
}

// ---------- i8 GEMM body: 128x128 tile, BK=64, 3-stage pipeline (R12 best) ----------
__device__ __forceinline__ void gemm_body(const char* __restrict__ A,
                                          const char* __restrict__ B,
                                          float* __restrict__ C,
                                          int m0, int n0, int N, int K,
                                          float scale, unsigned* out_amax,
                                          char* Asm, char* Bsm) {
    const int tid  = threadIdx.x;
    const int lane = tid & 63;
    const int wave = tid >> 6;
    const int wr = (wave >> 1) * 64;
    const int wc = (wave & 1) * 64;
    const int l15 = lane & 15;
    const int l4  = lane >> 4;
    const int cx  = (l4 ^ (l15 & 3)) * 16;          // swizzled frag-read col
    const int r0  = tid >> 2;                        // staging row
    const int sc  = ((tid & 3) ^ ((tid >> 2) & 3)) * 16;  // pre-swizzled source col

    i32x4 acc[4][4];
    #pragma unroll
    for (int i = 0; i < 4; ++i)
        #pragma unroll
        for (int j = 0; j < 4; ++j) acc[i][j] = (i32x4){0, 0, 0, 0};

    auto STAGE = [&](int buf, int k0) {
        GLD16(&A[(size_t)(m0 + r0) * K + k0 + sc],      &Asm[buf * 8192 + wave * 1024]);
        GLD16(&A[(size_t)(m0 + 64 + r0) * K + k0 + sc], &Asm[buf * 8192 + 4096 + wave * 1024]);
        GLD16(&B[(size_t)(n0 + r0) * K + k0 + sc],      &Bsm[buf * 8192 + wave * 1024]);
        GLD16(&B[(size_t)(n0 + 64 + r0) * K + k0 + sc], &Bsm[buf * 8192 + 4096 + wave * 1024]);
    };

    const int NT = K >> 6;
    STAGE(0, 0);
    STAGE(1, 64);
    int cur = 0;
    for (int t = 0; t < NT; ++t) {
        if (t + 1 < NT) {
            asm volatile("s_waitcnt vmcnt(4)" ::: "memory");   // STAGE(t) landed
        } else {
            asm volatile("s_waitcnt vmcnt(0)" ::: "memory");   // last: drain all
        }
        __builtin_amdgcn_sched_barrier(0);
        __builtin_amdgcn_s_barrier();                          // raw: no vm drain
        __builtin_amdgcn_sched_barrier(0);
        if (t + 2 < NT) {
            int nb = cur + 2; if (nb >= 3) nb -= 3;
            STAGE(nb, (t + 2) << 6);                           // overwrites buf[t-1]
        }
        i32x4 af[4], bfr[4];
        #pragma unroll
        for (int i = 0; i < 4; ++i)
            af[i] = *(const i32x4*)&Asm[cur * 8192 + (wr + i * 16 + l15) * 64 + cx];
        #pragma unroll
        for (int j = 0; j < 4; ++j)
            bfr[j] = *(const i32x4*)&Bsm[cur * 8192 + (wc + j * 16 + l15) * 64 + cx];
        #pragma unroll
        for (int i = 0; i < 4; ++i)
            #pragma unroll
            for (int j = 0; j < 4; ++j)
                acc[i][j] = __builtin_amdgcn_mfma_i32_16x16x64_i8(af[i], bfr[j], acc[i][j], 0, 0, 0);
        cur += 1; if (cur == 3) cur = 0;
    }

    float lm = 0.0f;
    #pragma unroll
    for (int i = 0; i < 4; ++i)
        #pragma unroll
        for (int j = 0; j < 4; ++j)
            #pragma unroll
            for (int r = 0; r < 4; ++r) {
                int row = m0 + wr + i * 16 + l4 * 4 + r;
                int col = n0 + wc + j * 16 + l15;
                float v = (float)acc[i][j][r] * scale;
                C[(size_t)row * N + col] = v;
                lm = fmaxf(lm, fabsf(v));
            }
    __syncthreads();   // re-align waves before block_amax
    if (out_amax) block_amax_atomic(lm, out_amax);
}

// fused Q,K,V projections: grid 768 = 16 m-tiles x 48 n-blocks (32 Q | 8 K | 8 V)
__global__ __launch_bounds__(256) void gemm_qkv_kernel(const char* __restrict__ Aq,
                                                       const char* __restrict__ Wqq,
                                                       const char* __restrict__ Wkq,
                                                       const char* __restrict__ Wvq,
                                                       float* __restrict__ qf,
                                                       float* __restrict__ kf,
                                                       float* __restrict__ vf,
                                                       const unsigned* __restrict__ slots,
                                                       unsigned* v_amax) {
    __shared__ __align__(16) char Asm[3 * 8192];
    __shared__ __align__(16) char Bsm[3 * 8192];
    int bid = blockIdx.x;
    int swz = (bid & 7) * 96 + (bid >> 3);      // bijective XCD swizzle (768 % 8 == 0)
    int x = swz & 15, y = swz >> 4;
    const char* B; float* C; int N, nb; const unsigned* sB; unsigned* am = nullptr;
    if (y < 32)      { B = Wqq; C = qf; N = NH * HD;  nb = y;      sB = slots + 1; }
    else if (y < 40) { B = Wkq; C = kf; N = NKV * HD; nb = y - 32; sB = slots + 2; }
    else             { B = Wvq; C = vf; N = NKV * HD; nb = y - 40; sB = slots + 3; am = v_amax; }
    float scale = slot_scale(slots + 0) * slot_scale(sB);
    gemm_body(Aq, B, C, x * 128, nb * 128, N, HIDD, scale, am, Asm, Bsm);
}

// O-projection: grid 512 = 16 x 32
__global__ __launch_bounds__(256) void gemm_o_kernel(const char* __restrict__ A,
                                                     const char* __restrict__ Woq,
                                                     float* __restrict__ C,
                                                     const unsigned* __restrict__ slots) {
    __shared__ __align__(16) char Asm[3 * 8192];
    __shared__ __align__(16) char Bsm[3 * 8192];
    int bid = blockIdx.x;
    int swz = (bid & 7) * 64 + (bid >> 3);      // 512 % 8 == 0
    int x = swz & 15, y = swz >> 4;
    float scale = slot_scale(slots + 8) * slot_scale(slots + 4);
    gemm_body(A, Woq, C, x * 128, y * 128, NH * HD, HIDD, scale, nullptr, Asm, Bsm);
}

// ---------- RMSNorm + RoPE for q (y=0) and k (y=1), in-place, + absmax ----------
// cos/sin symmetry: emb = concat([freqs,freqs]) -> cos[s][d] == cos[s][d+64];
// load only cols 0..63 (one factor per lane serves both halves).
__global__ __launch_bounds__(256) void rmsrope2_kernel(float* __restrict__ qx,
                                                       float* __restrict__ kx,
                                                       const float* __restrict__ cosb,
                                                       const float* __restrict__ sinb,
                                                       const float* __restrict__ qw,
                                                       const float* __restrict__ kw,
                                                       unsigned* slots) {
    const int which = blockIdx.y;
    float* x = which ? kx : qx;
    const float* w = which ? kw : qw;
    const int s_shift = which ? 3 : 5;
    const int nrows = which ? (S_LEN * NKV) : (S_LEN * NH);
    unsigned* slot = slots + (which ? 6 : 5);

    const int lane = threadIdx.x & 63;
    const int wid  = threadIdx.x >> 6;
    const float wa = w[lane];
    const float wb = w[lane + 64];
    float lm = 0.0f;
    for (int row = blockIdx.x * 4 + wid; row < nrows; row += gridDim.x * 4) {
        int s = row >> s_shift;
        float* xr = x + (size_t)row * 128;
        float a = xr[lane], b = xr[lane + 64];
        float ss = a * a + b * b;
        #pragma unroll
        for (int o = 32; o; o >>= 1) ss += __shfl_xor(ss, o);
        float inv = 1.0f / sqrtf(ss * (1.0f / 128.0f) + 1e-5f);
        float ya = (a * inv) * wa;
        float yb = (b * inv) * wb;
        float c = cosb[(size_t)s * 128 + lane];   // == cosb[s][lane+64]
        float sn = sinb[(size_t)s * 128 + lane];  // == sinb[s][lane+64]
        float o0 = ya * c - yb * sn;
        float o1 = yb * c + ya * sn;
        xr[lane] = o0;
        xr[lane + 64] = o1;
        lm = fmaxf(lm, fmaxf(fabsf(o0), fabsf(o1)));
    }
    block_amax_atomic(lm, slot);
}

// ---------- merged quantize: v transpose (bx<1024) + q/k reorder ----------
__global__ __launch_bounds__(256) void quant_qkv_kernel(const float* __restrict__ qx,
                                                        const float* __restrict__ kx,
                                                        const float* __restrict__ vx,
                                                        const unsigned* slots,
                                                        char* __restrict__ qq,
                                                        char* __restrict__ kq,
                                                        char* __restrict__ vtq) {
    const int bx = blockIdx.x;
    if (bx < 1024) {
        __shared__ unsigned char t8[64][36];
        const float s = slot_scale(slots + 7);
        const int t   = threadIdx.x;
        const int kvh = bx >> 7;
        const int rem = bx & 127;
        const int d0  = (rem & 3) * 32;
        const int sp0 = (rem >> 2) * 64;
        const int dl = t & 31;
        const int sb = t >> 5;
        #pragma unroll
        for (int j = 0; j < 8; ++j) {
            int spl = sb + j * 8;
            float v = vx[((size_t)(sp0 + spl) * NKV + kvh) * 128 + d0 + dl];
            t8[spl][dl] = (unsigned char)qint(v, s);
        }
        __syncthreads();
        const int dd = t >> 3;
        const int ch = t & 7;
        unsigned lo = 0, hi = 0;
        #pragma unroll
        for (int j = 0; j < 4; ++j) lo |= (unsigned)t8[ch * 8 + j][dd] << (8 * j);
        #pragma unroll
        for (int j = 0; j < 4; ++j) hi |= (unsigned)t8[ch * 8 + 4 + j][dd] << (8 * j);
        *(uint2*)&vtq[((size_t)kvh * 128 + d0 + dd) * S_LEN + sp0 + ch * 8] = make_uint2(lo, hi);
        return;
    }
    int tid = (bx - 1024) * 256 + threadIdx.x;         // one per 4 elements
    const int qtot4 = S_LEN * NH * HD / 4;
    if (tid < qtot4) {
        float s = slot_scale(slots + 5);
        int e = tid * 4;
        int d  = e & 127;
        int h  = (e >> 7) & 31;
        int sp = e >> 12;
        float4 v = *(const float4*)&qx[e];
        uchar4 o;
        o.x = (unsigned char)qint(v.x, s); o.y = (unsigned char)qint(v.y, s);
        o.z = (unsigned char)qint(v.z, s); o.w = (unsigned char)qint(v.w, s);
        *(uchar4*)&qq[((size_t)h * S_LEN + sp) * 128 + d] = o;
    } else {
        tid -= qtot4;
        float s = slot_scale(slots + 6);
        int e = tid * 4;
        int d  = e & 127;
        int h  = (e >> 7) & 7;
        int sp = e >> 10;
        float4 v = *(const float4*)&kx[e];
        uchar4 o;
        o.x = (unsigned char)qint(v.x, s); o.y = (unsigned char)qint(v.y, s);
        o.z = (unsigned char)qint(v.z, s); o.w = (unsigned char)qint(v.w, s);
        *(uchar4*)&kq[((size_t)h * S_LEN + sp) * 128 + d] = o;
    }
}

// ---------- attention: two-pass flash, all-int8 MFMA, 8-wave TLP tile pair ----------
__global__ __launch_bounds__(512) void attn_kernel(const char* __restrict__ Qq,
                                                   const char* __restrict__ Kq,
                                                   const char* __restrict__ Vt,
                                                   const unsigned* sq_slot,
                                                   const unsigned* sk_slot,
                                                   const unsigned* sv_slot,
                                                   float* __restrict__ O,
                                                   unsigned* amax_slot) {
    __shared__ __align__(16) char Klds[64 * 144];     // stride 144B
    __shared__ __align__(16) char Vlds[128 * 80];     // stride 80B
    __shared__ __align__(16) char plds[8][16 * 80];   // per-wave P tile

    const int tid  = threadIdx.x;
    const int lane = tid & 63;
    const int wave = tid >> 6;          // 0..7
    const int mw   = wave & 3;          // sub-row within tile
    const int h  = blockIdx.y;
    const int kv = h >> 2;
    const int l15 = lane & 15;
    const int l4  = lane >> 4;
    const size_t kvS = (size_t)kv * S_LEN;

    const int qtS = blockIdx.x;           // 0..15
    const int qtB = 31 - qtS;             // 16..31
    const int my_qt = (wave < 4) ? qtB : qtS;
    const int qr0 = my_qt * 64 + mw * 16;

    const float sq = slot_scale(sq_slot);
    const float sk = slot_scale(sk_slot);
    const float sv = slot_scale(sv_slot);
    const float qs2 = sq * sk * 0.08838834764831845f * 1.4426950408889634f; // *log2(e)
    const float osc = (1.0f / 127.0f) * sv;   // s_p exactly 1/127 (row 0 => max p = 1.0)
    const float NEG = -1e30f;

    const int krow = tid >> 3, kcol = (tid & 7) * 16;   // 64 x 128B
    const int vrow = tid >> 2, vcol = (tid & 3) * 16;   // 128 x 64B

    i32x4 qf2[2];
    {
        const char* qp = Qq + ((size_t)h * S_LEN + qr0 + l15) * 128 + l4 * 16;
        qf2[0] = *(const i32x4*)(qp);
        qf2[1] = *(const i32x4*)(qp + 64);
    }

    auto qk_block = [&](int hb) -> i32x4 {
        i32x4 sacc = {0, 0, 0, 0};
        #pragma unroll
        for (int c = 0; c < 2; ++c) {
            i32x4 kfa = *(const i32x4*)&Klds[(hb * 16 + l15) * 144 + c * 64 + l4 * 16];
            sacc = __builtin_amdgcn_mfma_i32_16x16x64_i8(kfa, qf2[c], sacc, 0, 0, 0);
        }
        return sacc;
    };

    // ================= pass 1: lane-local online m,l (my tile only) ==========
    float m_l = NEG, l_l = 0.0f;

    auto p1_interior = [&](int hb) {
        i32x4 sacc = qk_block(hb);
        float x0 = (float)sacc[0] * qs2, x1 = (float)sacc[1] * qs2;
        float x2 = (float)sacc[2] * qs2, x3 = (float)sacc[3] * qs2;
        float bm = fmaxf(fmaxf(x0, x1), fmaxf(x2, x3));
        float mn = fmaxf(m_l, bm);
        float ps = exp2_fast(x0 - mn) + exp2_fast(x1 - mn)
                 + exp2_fast(x2 - mn) + exp2_fast(x3 - mn);
        l_l = l_l * exp2_fast(m_l - mn) + ps;
        m_l = mn;
    };
    auto p1_diag = [&](int hb) {
        i32x4 sacc = qk_block(hb);
        float x[4];
        #pragma unroll
        for (int r = 0; r < 4; ++r) {
            float v = (float)sacc[r] * qs2;
            x[r] = ((l4 * 4 + r) > l15) ? NEG : v;
        }
        float bm = fmaxf(fmaxf(x[0], x[1]), fmaxf(x[2], x[3]));
        float mn = fmaxf(m_l, bm);
        float ps = exp2_fast(x[0] - mn) + exp2_fast(x[1] - mn)
                 + exp2_fast(x[2] - mn) + exp2_fast(x[3] - mn);
        l_l = l_l * exp2_fast(m_l - mn) + ps;
        m_l = mn;
    };

    i32x4 kreg = *(const i32x4*)&Kq[(kvS + krow) * 128 + kcol];
    #pragma unroll 1
    for (int kc = 0; kc <= qtB; ++kc) {
        __syncthreads();
        *(i32x4*)&Klds[krow * 144 + kcol] = kreg;
        __syncthreads();
        if (kc < qtB)
            kreg = *(const i32x4*)&Kq[(kvS + (kc + 1) * 64 + krow) * 128 + kcol];
        if (kc < my_qt) {
            p1_interior(0); p1_interior(1); p1_interior(2); p1_interior(3);
        } else if (kc == my_qt) {
            #pragma unroll
            for (int hb = 0; hb < 4; ++hb) {
                if (hb < mw) p1_interior(hb);
                else if (hb == mw) p1_diag(hb);
            }
        }
    }
    float cmy;
    {
        float m2 = fmaxf(m_l, __shfl_xor(m_l, 16));
        float mfin = fmaxf(m2, __shfl_xor(m2, 32));
        float t = l_l * exp2_fast(m_l - mfin);
        t += __shfl_xor(t, 16);
        t += __shfl_xor(t, 32);
        cmy = mfin - log2_fast(127.0f / t);
    }

    // ================= pass 2: quantized P @ V (i8), my tile only ============
    i32x4 oacc[8];
    #pragma unroll
    for (int dt = 0; dt < 8; ++dt) oacc[dt] = (i32x4){0, 0, 0, 0};

    auto p2_interior = [&](int hb) -> unsigned {
        i32x4 sacc = qk_block(hb);
        unsigned pack = 0;
        #pragma unroll
        for (int r = 0; r < 4; ++r) {
            float pq = rintf(exp2_fast(fmaf((float)sacc[r], qs2, -cmy)));
            pack |= ((unsigned)(int)pq) << (8 * r);
        }
        return pack;
    };
    auto p2_diag = [&](int hb) -> unsigned {
        i32x4 sacc = qk_block(hb);
        unsigned pack = 0;
        #pragma unroll
        for (int r = 0; r < 4; ++r) {
            float p = exp2_fast(fmaf((float)sacc[r], qs2, -cmy));
            float pq = ((l4 * 4 + r) > l15) ? 0.0f : rintf(p);
            pack |= ((unsigned)(int)pq) << (8 * r);
        }
        return pack;
    };
    auto pv8 = [&]() {
        i32x4 pf = *(const i32x4*)&plds[wave][l15 * 80 + l4 * 16];
        __builtin_amdgcn_s_setprio(1);
        #pragma unroll
        for (int dt = 0; dt < 8; ++dt) {
            i32x4 vfb = *(const i32x4*)&Vlds[(dt * 16 + l15) * 80 + l4 * 16];
            oacc[dt] = __builtin_amdgcn_mfma_i32_16x16x64_i8(pf, vfb, oacc[dt], 0, 0, 0);
        }
        __builtin_amdgcn_s_setprio(0);
    };

    kreg = *(const i32x4*)&Kq[(kvS + krow) * 128 + kcol];
    i32x4 vreg = *(const i32x4*)&Vt[((size_t)kv * 128 + vrow) * S_LEN + vcol];
    #pragma unroll 1
    for (int kc = 0; kc <= qtB; ++kc) {
        __syncthreads();
        *(i32x4*)&Klds[krow * 144 + kcol] = kreg;
        *(i32x4*)&Vlds[vrow * 80 + vcol] = vreg;
        __syncthreads();
        if (kc < qtB) {
            kreg = *(const i32x4*)&Kq[(kvS + (kc + 1) * 64 + krow) * 128 + kcol];
            vreg = *(const i32x4*)&Vt[((size_t)kv * 128 + vrow) * S_LEN + (kc + 1) * 64 + vcol];
        }
        if (kc < my_qt) {
            #pragma unroll
            for (int hb = 0; hb < 4; ++hb)
                *(unsigned*)&plds[wave][l15 * 80 + hb * 16 + l4 * 4] = p2_interior(hb);
            pv8();
        } else if (kc == my_qt) {
            #pragma unroll
            for (int hb = 0; hb < 4; ++hb) {
                unsigned pack = 0;
                if (hb < mw) pack = p2_interior(hb);
                else if (hb == mw) pack = p2_diag(hb);
                *(unsigned*)&plds[wave][l15 * 80 + hb * 16 + l4 * 4] = pack;
            }
            pv8();
        }
    }

    float lm = 0.0f;
    #pragma unroll
    for (int dt = 0; dt < 8; ++dt)
        #pragma unroll
        for (int r = 0; r < 4; ++r) {
            float v = (float)oacc[dt][r] * osc;
            O[(size_t)(qr0 + l4 * 4 + r) * (NH * 128) + h * 128 + dt * 16 + l15] = v;
            lm = fmaxf(lm, fabsf(v));
        }
    block_amax_atomic(lm, amax_slot);
}

// ---------- host ----------
extern "C" void kernel_launch(void* const* d_in, const int* in_sizes, int n_in,
                              void* d_out, int out_size, void* d_ws, size_t ws_size,
                              hipStream_t stream) {
    const float* hs   = (const float*)d_in[0];
    const float* cosb = (const float*)d_in[1];
    const float* sinb = (const float*)d_in[2];
    const float* Wq   = (const float*)d_in[4];
    const float* Wk   = (const float*)d_in[5];
    const float* Wv   = (const float*)d_in[6];
    const float* Wo   = (const float*)d_in[7];
    const float* qnw  = (const float*)d_in[8];
    const float* knw  = (const float*)d_in[9];
    float* out = (float*)d_out;

    char* ws = (char*)d_ws;
    unsigned* slots = (unsigned*)ws;
    // slots: 0 hs, 1 Wq, 2 Wk, 3 Wv, 4 Wo, 5 q, 6 k, 7 v, 8 attn
    size_t off = 256;
    auto take = [&](size_t bytes) { size_t o = off; off += (bytes + 255) & ~(size_t)255; return o; };
    char*  hsq  = (char*)(ws + take((size_t)S_LEN * HIDD));
    char*  Wqq  = (char*)(ws + take((size_t)NH * HD * HIDD));
    char*  Wkq  = (char*)(ws + take((size_t)NKV * HD * HIDD));
    char*  Wvq  = (char*)(ws + take((size_t)NKV * HD * HIDD));
    char*  Woq  = (char*)(ws + take((size_t)HIDD * NH * HD));
    float* qf   = (float*)(ws + take((size_t)S_LEN * NH * HD * 4));
    float* kf   = (float*)(ws + take((size_t)S_LEN * NKV * HD * 4));
    float* vf   = (float*)(ws + take((size_t)S_LEN * NKV * HD * 4));
    char*  qq   = (char*)(ws + take((size_t)NH * S_LEN * HD));
    char*  kq   = (char*)(ws + take((size_t)NKV * S_LEN * HD));
    char*  vtq  = (char*)(ws + take((size_t)NKV * HD * S_LEN));
    float* attnf = qf;     // q f32 dead after quant_qkv
    char*  attnq = hsq;    // hs_q dead after the projections

    hipMemsetAsync(ws, 0, 64, stream);

    const size_t n_hs = (size_t)S_LEN * HIDD;
    const size_t n_wq = (size_t)NH * HD * HIDD;
    const size_t n_wk = (size_t)NKV * HD * HIDD;

    Amax5Args aa;
    aa.p[0] = hs; aa.p[1] = Wq; aa.p[2] = Wk; aa.p[3] = Wv; aa.p[4] = Wo;
    aa.n4[0] = n_hs / 4; aa.n4[1] = n_wq / 4; aa.n4[2] = n_wk / 4;
    aa.n4[3] = n_wk / 4; aa.n4[4] = n_wq / 4;
    absmax5_kernel<<<dim3(512, 5), 256, 0, stream>>>(aa, slots);

    Quant5Args qa;
    qa.p[0] = hs; qa.p[1] = Wq; qa.p[2] = Wk; qa.p[3] = Wv; qa.p[4] = Wo;
    qa.o[0] = hsq; qa.o[1] = Wqq; qa.o[2] = Wkq; qa.o[3] = Wvq; qa.o[4] = Woq;
    qa.n4[0] = n_hs / 4; qa.n4[1] = n_wq / 4; qa.n4[2] = n_wk / 4;
    qa.n4[3] = n_wk / 4; qa.n4[4] = n_wq / 4;
    quant5_kernel<<<dim3(1024, 5), 256, 0, stream>>>(qa, slots);

    gemm_qkv_kernel<<<768, 256, 0, stream>>>(hsq, Wqq, Wkq, Wvq, qf, kf, vf,
                                             slots, slots + 7);

    rmsrope2_kernel<<<dim3(1024, 2), 256, 0, stream>>>(qf, kf, cosb, sinb, qnw, knw, slots);

    quant_qkv_kernel<<<1024 + 10240, 256, 0, stream>>>(qf, kf, vf, slots, qq, kq, vtq);

    attn_kernel<<<dim3(16, NH), 512, 0, stream>>>(qq, kq, vtq,
                                                  slots + 5, slots + 6, slots + 7,
                                                  attnf, slots + 8);

    quant_kernel<<<2048, 256, 0, stream>>>(attnf, n_hs / 4, slots + 8, attnq);
    gemm_o_kernel<<<512, 256, 0, stream>>>(attnq, Woq, out, slots);
    (void)in_sizes; (void)n_in; (void)out_size; (void)ws_size;
}